// Round 1
// baseline (686.438 us; speedup 1.0000x reference)
//
#include <hip/hip_runtime.h>
#include <hip/hip_bf16.h>
#include <math.h>

#define NA 10000
#define NE 256000
#define FDIM 128
#define F3 384
#define NRBF 20
#define NLAYERS 3
#define NMOLS 100
#define FH 64
#define CUTOFF_F 5.0f
#define EPS_F 1e-8f
#define PI_F 3.14159265358979323846f

__device__ __forceinline__ float silu_f(float x) { return x / (1.0f + expf(-x)); }

// ---------------- geometry (layer-invariant, per edge) ----------------
__global__ __launch_bounds__(256) void geom_kernel(
    const float* __restrict__ xyz, const int* __restrict__ nbrs,
    float* __restrict__ unitv, float* __restrict__ rbfc, float* __restrict__ fcut) {
  int e = blockIdx.x * 256 + threadIdx.x;
  if (e >= NE) return;
  int i = nbrs[2 * e + 0], j = nbrs[2 * e + 1];
  float rx = xyz[3 * j + 0] - xyz[3 * i + 0];
  float ry = xyz[3 * j + 1] - xyz[3 * i + 1];
  float rz = xyz[3 * j + 2] - xyz[3 * i + 2];
  float d = sqrtf(rx * rx + ry * ry + rz * rz + EPS_F);
  float invd = 1.0f / d;
  unitv[3 * e + 0] = rx * invd;
  unitv[3 * e + 1] = ry * invd;
  unitv[3 * e + 2] = rz * invd;
  float fc = 0.0f;
  if (d < CUTOFF_F) fc = 0.5f * (cosf(PI_F * d / CUTOFF_F) + 1.0f);
  fcut[e] = fc;
  float base = PI_F * d / CUTOFF_F;
  float sc = invd * fc;  // rbfc = sin(n*pi*d/c)/d * fcut
#pragma unroll
  for (int k = 0; k < NRBF; k++) rbfc[e * NRBF + k] = sinf((float)(k + 1) * base) * sc;
}

// ---------------- CSR build over idx_i (skip fcut==0 edges) ----------------
__global__ __launch_bounds__(256) void count_kernel(
    const int* __restrict__ nbrs, const float* __restrict__ fcut, int* __restrict__ counts) {
  int e = blockIdx.x * 256 + threadIdx.x;
  if (e >= NE) return;
  if (fcut[e] > 0.0f) atomicAdd(&counts[nbrs[2 * e]], 1);
}

__global__ __launch_bounds__(1024) void scan_kernel(const int* __restrict__ counts,
                                                    int* __restrict__ offs) {
  __shared__ int buf[1024];
  __shared__ int carry_s;
  int t = threadIdx.x;
  if (t == 0) { carry_s = 0; offs[0] = 0; }
  __syncthreads();
  for (int base = 0; base < NA; base += 1024) {
    int idx = base + t;
    int val = (idx < NA) ? counts[idx] : 0;
    buf[t] = val;
    __syncthreads();
    for (int off = 1; off < 1024; off <<= 1) {
      int other = (t >= off) ? buf[t - off] : 0;
      __syncthreads();
      buf[t] += other;
      __syncthreads();
    }
    if (idx < NA) offs[idx + 1] = carry_s + buf[t];
    __syncthreads();
    if (t == 1023) carry_s += buf[1023];
    __syncthreads();
  }
}

__global__ __launch_bounds__(256) void fill_kernel(
    const int* __restrict__ nbrs, const float* __restrict__ fcut,
    const int* __restrict__ offs, int* __restrict__ cursor,
    int* __restrict__ csr_eid, int* __restrict__ csr_j) {
  int e = blockIdx.x * 256 + threadIdx.x;
  if (e >= NE) return;
  if (fcut[e] <= 0.0f) return;
  int i = nbrs[2 * e];
  int pos = offs[i] + atomicAdd(&cursor[i], 1);
  csr_eid[pos] = e;
  csr_j[pos] = nbrs[2 * e + 1];
}

// ---------------- init: s = emb[z], v = 0 ----------------
__global__ __launch_bounds__(256) void init_kernel(
    const float* __restrict__ emb, const int* __restrict__ z,
    float* __restrict__ s, float* __restrict__ vA) {
  int t = blockIdx.x * 256 + threadIdx.x;
  if (t < NA * 3 * FDIM) vA[t] = 0.0f;
  if (t < NA * FDIM) {
    int n = t >> 7, f = t & 127;
    s[t] = emb[z[n] * FDIM + f];
  }
}

// ---------------- message MLP: phi = silu(s@W1+b1)@W2+b2, (N,384) ----------------
__global__ __launch_bounds__(256) void msg_kernel(
    const float* __restrict__ s, const float* __restrict__ W1, const float* __restrict__ b1,
    const float* __restrict__ W2, const float* __restrict__ b2, float* __restrict__ phi) {
  __shared__ float s_lds[8][FDIM];
  __shared__ float h_lds[8][FDIM];
  int a0 = blockIdx.x * 8;
  int t = threadIdx.x;
  for (int q = t; q < 8 * FDIM; q += 256) ((float*)s_lds)[q] = s[a0 * FDIM + q];
  __syncthreads();
  int g = t & 127, half = t >> 7;
  float acc[4];
  float bb = b1[g];
#pragma unroll
  for (int q = 0; q < 4; q++) acc[q] = bb;
  for (int k = 0; k < FDIM; k++) {
    float w = W1[k * FDIM + g];
#pragma unroll
    for (int q = 0; q < 4; q++) acc[q] += s_lds[half * 4 + q][k] * w;
  }
#pragma unroll
  for (int q = 0; q < 4; q++) h_lds[half * 4 + q][g] = silu_f(acc[q]);
  __syncthreads();
  float a2[4][3];
#pragma unroll
  for (int c = 0; c < 3; c++) {
    float b = b2[c * FDIM + g];
#pragma unroll
    for (int q = 0; q < 4; q++) a2[q][c] = b;
  }
  for (int k = 0; k < FDIM; k++) {
    float w0 = W2[k * F3 + g], w1 = W2[k * F3 + FDIM + g], w2 = W2[k * F3 + 2 * FDIM + g];
#pragma unroll
    for (int q = 0; q < 4; q++) {
      float hv = h_lds[half * 4 + q][k];
      a2[q][0] += hv * w0; a2[q][1] += hv * w1; a2[q][2] += hv * w2;
    }
  }
#pragma unroll
  for (int q = 0; q < 4; q++) {
    int n = a0 + half * 4 + q;
    phi[n * F3 + g] = a2[q][0];
    phi[n * F3 + FDIM + g] = a2[q][1];
    phi[n * F3 + 2 * FDIM + g] = a2[q][2];
  }
}

// ---------------- edge aggregation: one block per atom i, no atomics ----------------
// v layout: (N, 3, F): v[n*3F + c*F + f] == v_ref[n, f, c]
__global__ __launch_bounds__(128) void edge_kernel(
    const float* __restrict__ phi, const float* __restrict__ v_in,
    float* __restrict__ v_out, float* __restrict__ s,
    const float* __restrict__ dW, const float* __restrict__ db,
    const int* __restrict__ offs, const int* __restrict__ csr_eid,
    const int* __restrict__ csr_j, const float* __restrict__ rbfc,
    const float* __restrict__ fcut, const float* __restrict__ unitv) {
  int i = blockIdx.x;
  int f = threadIdx.x;
  float wd0[NRBF], wd1[NRBF], wd2[NRBF];  // register-cached dist_W columns
#pragma unroll
  for (int k = 0; k < NRBF; k++) {
    wd0[k] = dW[k * F3 + f];
    wd1[k] = dW[k * F3 + FDIM + f];
    wd2[k] = dW[k * F3 + 2 * FDIM + f];
  }
  float db0 = db[f], db1 = db[FDIM + f], db2 = db[2 * FDIM + f];
  float acc_s = 0.f, av0 = 0.f, av1 = 0.f, av2 = 0.f;
  int p0 = offs[i], p1 = offs[i + 1];
  for (int p = p0; p < p1; p++) {
    int eid = csr_eid[p];
    int j = csr_j[p];
    float fc = fcut[eid];
    float ux = unitv[3 * eid + 0], uy = unitv[3 * eid + 1], uz = unitv[3 * eid + 2];
    const float* rb = rbfc + eid * NRBF;
    float w0 = db0 * fc, w1 = db1 * fc, w2 = db2 * fc;
#pragma unroll
    for (int k = 0; k < NRBF; k++) {
      float r = rb[k];
      w0 += r * wd0[k]; w1 += r * wd1[k]; w2 += r * wd2[k];
    }
    const float* ph = phi + j * F3;
    float i0 = ph[f] * w0;
    float i1 = ph[FDIM + f] * w1;
    float i2 = ph[2 * FDIM + f] * w2;
    const float* vj = v_in + j * 3 * FDIM;
    acc_s += i0;
    av0 += i1 * vj[f] + i2 * ux;
    av1 += i1 * vj[FDIM + f] + i2 * uy;
    av2 += i1 * vj[2 * FDIM + f] + i2 * uz;
  }
  s[i * FDIM + f] += acc_s;
  const float* vi = v_in + i * 3 * FDIM;
  float* vo = v_out + i * 3 * FDIM;
  vo[f] = vi[f] + av0;
  vo[FDIM + f] = vi[FDIM + f] + av1;
  vo[2 * FDIM + f] = vi[2 * FDIM + f] + av2;
}

// ---------------- update block: u_v, v_v, gated MLP, in-place s/v ----------------
__global__ __launch_bounds__(256) void upd_kernel(
    float* __restrict__ s, float* __restrict__ v,
    const float* __restrict__ U, const float* __restrict__ V,
    const float* __restrict__ W1, const float* __restrict__ b1,
    const float* __restrict__ W2, const float* __restrict__ b2) {
  __shared__ float v_lds[8][3][FDIM];
  __shared__ float cat_lds[8][2 * FDIM];  // [s | vnorm]
  __shared__ float h_lds[8][FDIM];
  int a0 = blockIdx.x * 8;
  int t = threadIdx.x;
  for (int q = t; q < 8 * 3 * FDIM; q += 256) ((float*)v_lds)[q] = v[a0 * 3 * FDIM + q];
  for (int q = t; q < 8 * FDIM; q += 256) {
    int a = q >> 7, f = q & 127;
    cat_lds[a][f] = s[(a0 + a) * FDIM + f];
  }
  __syncthreads();
  int g = t & 127, half = t >> 7;
  // u_v[n,g,c] = sum_f v[n,f,c]*U[f,g] ; same for V. Thread owns (g, 4 atoms).
  float aU[4][3], aV[4][3];
#pragma unroll
  for (int q = 0; q < 4; q++)
#pragma unroll
    for (int c = 0; c < 3; c++) { aU[q][c] = 0.f; aV[q][c] = 0.f; }
  for (int k = 0; k < FDIM; k++) {
    float uw = U[k * FDIM + g], vw = V[k * FDIM + g];
#pragma unroll
    for (int q = 0; q < 4; q++) {
      int a = half * 4 + q;
#pragma unroll
      for (int c = 0; c < 3; c++) {
        float vv = v_lds[a][c][k];  // wave-uniform -> LDS broadcast
        aU[q][c] += vv * uw;
        aV[q][c] += vv * vw;
      }
    }
  }
#pragma unroll
  for (int q = 0; q < 4; q++) {
    int a = half * 4 + q;
    cat_lds[a][FDIM + g] =
        sqrtf(aV[q][0] * aV[q][0] + aV[q][1] * aV[q][1] + aV[q][2] * aV[q][2] + EPS_F);
  }
  __syncthreads();
  float ah[4];
  float b1v = b1[g];
#pragma unroll
  for (int q = 0; q < 4; q++) ah[q] = b1v;
  for (int k = 0; k < 2 * FDIM; k++) {
    float w = W1[k * FDIM + g];
#pragma unroll
    for (int q = 0; q < 4; q++) ah[q] += cat_lds[half * 4 + q][k] * w;
  }
#pragma unroll
  for (int q = 0; q < 4; q++) h_lds[half * 4 + q][g] = silu_f(ah[q]);
  __syncthreads();
  float aa[4][3];
#pragma unroll
  for (int c = 0; c < 3; c++) {
    float b = b2[c * FDIM + g];
#pragma unroll
    for (int q = 0; q < 4; q++) aa[q][c] = b;
  }
  for (int k = 0; k < FDIM; k++) {
    float w0 = W2[k * F3 + g], w1 = W2[k * F3 + FDIM + g], w2 = W2[k * F3 + 2 * FDIM + g];
#pragma unroll
    for (int q = 0; q < 4; q++) {
      float hv = h_lds[half * 4 + q][k];
      aa[q][0] += hv * w0; aa[q][1] += hv * w1; aa[q][2] += hv * w2;
    }
  }
#pragma unroll
  for (int q = 0; q < 4; q++) {
    int a = half * 4 + q;
    int n = a0 + a;
    float dotuv = 0.f;
#pragma unroll
    for (int c = 0; c < 3; c++) {
      dotuv += aU[q][c] * aV[q][c];
      v[n * 3 * FDIM + c * FDIM + g] = v_lds[a][c][g] + aa[q][0] * aU[q][c];
    }
    s[n * FDIM + g] += aa[q][1] * dotuv + aa[q][2];
  }
}

// ---------------- readout: atom MLP + molecule segment sum ----------------
__global__ __launch_bounds__(64) void readout_kernel(
    const float* __restrict__ s, const float* __restrict__ W1, const float* __restrict__ b1,
    const float* __restrict__ W2, const float* __restrict__ b2,
    const int* __restrict__ mol_idx, float* __restrict__ out) {
  int n = blockIdx.x;
  int t = threadIdx.x;
  float acc = b1[t];
  const float* sr = s + n * FDIM;
  for (int k = 0; k < FDIM; k++) acc += sr[k] * W1[k * FH + t];
  float val = silu_f(acc) * W2[t];
#pragma unroll
  for (int off = 32; off > 0; off >>= 1) val += __shfl_down(val, off, 64);
  if (t == 0) atomicAdd(&out[mol_idx[n]], val + b2[0]);
}

extern "C" void kernel_launch(void* const* d_in, const int* in_sizes, int n_in,
                              void* d_out, int out_size, void* d_ws, size_t ws_size,
                              hipStream_t stream) {
  const float* xyz = (const float*)d_in[0];
  const int* z = (const int*)d_in[1];
  const int* nbrs = (const int*)d_in[2];
  const int* mol = (const int*)d_in[3];
  const float* emb = (const float*)d_in[4];
  const float* msgW1 = (const float*)d_in[5];
  const float* msgb1 = (const float*)d_in[6];
  const float* msgW2 = (const float*)d_in[7];
  const float* msgb2 = (const float*)d_in[8];
  const float* distW = (const float*)d_in[9];
  const float* distb = (const float*)d_in[10];
  const float* updU = (const float*)d_in[11];
  const float* updV = (const float*)d_in[12];
  const float* updW1 = (const float*)d_in[13];
  const float* updb1 = (const float*)d_in[14];
  const float* updW2 = (const float*)d_in[15];
  const float* updb2 = (const float*)d_in[16];
  const float* rW1 = (const float*)d_in[17];
  const float* rb1 = (const float*)d_in[18];
  const float* rW2 = (const float*)d_in[19];
  const float* rb2 = (const float*)d_in[20];

  float* ws = (float*)d_ws;
  float* s = ws;      ws += (size_t)NA * FDIM;
  float* vA = ws;     ws += (size_t)NA * 3 * FDIM;
  float* vB = ws;     ws += (size_t)NA * 3 * FDIM;
  float* phi = ws;    ws += (size_t)NA * F3;
  float* rbfc = ws;   ws += (size_t)NE * NRBF;
  float* fcut = ws;   ws += (size_t)NE;
  float* unitv = ws;  ws += (size_t)NE * 3;
  int* counts = (int*)ws;
  int* cursor = counts + NA;
  int* offs = cursor + NA;
  int* csr_eid = offs + NA + 1;
  int* csr_j = csr_eid + NE;

  hipMemsetAsync(counts, 0, 2 * NA * sizeof(int), stream);
  hipMemsetAsync(d_out, 0, NMOLS * sizeof(float), stream);

  geom_kernel<<<NE / 256, 256, 0, stream>>>(xyz, nbrs, unitv, rbfc, fcut);
  count_kernel<<<NE / 256, 256, 0, stream>>>(nbrs, fcut, counts);
  scan_kernel<<<1, 1024, 0, stream>>>(counts, offs);
  fill_kernel<<<NE / 256, 256, 0, stream>>>(nbrs, fcut, offs, cursor, csr_eid, csr_j);
  init_kernel<<<(NA * 3 * FDIM + 255) / 256, 256, 0, stream>>>(emb, z, s, vA);

  float* vin = vA;
  float* vout = vB;
  for (int l = 0; l < NLAYERS; l++) {
    msg_kernel<<<NA / 8, 256, 0, stream>>>(s, msgW1 + (size_t)l * FDIM * FDIM,
                                           msgb1 + (size_t)l * FDIM,
                                           msgW2 + (size_t)l * FDIM * F3,
                                           msgb2 + (size_t)l * F3, phi);
    edge_kernel<<<NA, 128, 0, stream>>>(phi, vin, vout, s,
                                        distW + (size_t)l * NRBF * F3,
                                        distb + (size_t)l * F3,
                                        offs, csr_eid, csr_j, rbfc, fcut, unitv);
    upd_kernel<<<NA / 8, 256, 0, stream>>>(s, vout, updU + (size_t)l * FDIM * FDIM,
                                           updV + (size_t)l * FDIM * FDIM,
                                           updW1 + (size_t)l * 2 * FDIM * FDIM,
                                           updb1 + (size_t)l * FDIM,
                                           updW2 + (size_t)l * FDIM * F3,
                                           updb2 + (size_t)l * F3);
    float* tmp = vin; vin = vout; vout = tmp;
  }
  readout_kernel<<<NA, 64, 0, stream>>>(s, rW1, rb1, rW2, rb2, mol, (float*)d_out);
}

// Round 2
// 467.085 us; speedup vs baseline: 1.4696x; 1.4696x over previous
//
#include <hip/hip_runtime.h>
#include <hip/hip_bf16.h>
#include <math.h>

#define NA 10000
#define NE 256000
#define FDIM 128
#define F3 384
#define NRBF 20
#define NLAYERS 3
#define NMOLS 100
#define FH 64
#define CUTOFF_F 5.0f
#define EPS_F 1e-8f
#define PI_F 3.14159265358979323846f

typedef __attribute__((ext_vector_type(8))) short bf16x8;
typedef __attribute__((ext_vector_type(4))) float f32x4;

__device__ __forceinline__ float silu_f(float x) { return x / (1.0f + expf(-x)); }

__device__ __forceinline__ unsigned short f2bf(float x) {
  unsigned u = __float_as_uint(x);
  return (unsigned short)((u + 0x7FFFu + ((u >> 16) & 1u)) >> 16);
}

// ---------------- geometry (layer-invariant, per edge) ----------------
__global__ __launch_bounds__(256) void geom_kernel(
    const float* __restrict__ xyz, const int* __restrict__ nbrs,
    float* __restrict__ unitv, float* __restrict__ rbfc, float* __restrict__ fcut) {
  int e = blockIdx.x * 256 + threadIdx.x;
  if (e >= NE) return;
  int i = nbrs[2 * e + 0], j = nbrs[2 * e + 1];
  float rx = xyz[3 * j + 0] - xyz[3 * i + 0];
  float ry = xyz[3 * j + 1] - xyz[3 * i + 1];
  float rz = xyz[3 * j + 2] - xyz[3 * i + 2];
  float d = sqrtf(rx * rx + ry * ry + rz * rz + EPS_F);
  float invd = 1.0f / d;
  unitv[3 * e + 0] = rx * invd;
  unitv[3 * e + 1] = ry * invd;
  unitv[3 * e + 2] = rz * invd;
  float fc = 0.0f;
  if (d < CUTOFF_F) fc = 0.5f * (cosf(PI_F * d / CUTOFF_F) + 1.0f);
  fcut[e] = fc;
  float base = PI_F * d / CUTOFF_F;
  float sc = invd * fc;
#pragma unroll
  for (int k = 0; k < NRBF; k++) rbfc[e * NRBF + k] = sinf((float)(k + 1) * base) * sc;
}

// ---------------- CSR build over idx_i (skip fcut==0 edges) ----------------
__global__ __launch_bounds__(256) void count_kernel(
    const int* __restrict__ nbrs, const float* __restrict__ fcut, int* __restrict__ counts) {
  int e = blockIdx.x * 256 + threadIdx.x;
  if (e >= NE) return;
  if (fcut[e] > 0.0f) atomicAdd(&counts[nbrs[2 * e]], 1);
}

__global__ __launch_bounds__(1024) void scan_kernel(const int* __restrict__ counts,
                                                    int* __restrict__ offs) {
  __shared__ int buf[1024];
  __shared__ int carry_s;
  int t = threadIdx.x;
  if (t == 0) { carry_s = 0; offs[0] = 0; }
  __syncthreads();
  for (int base = 0; base < NA; base += 1024) {
    int idx = base + t;
    int val = (idx < NA) ? counts[idx] : 0;
    buf[t] = val;
    __syncthreads();
    for (int off = 1; off < 1024; off <<= 1) {
      int other = (t >= off) ? buf[t - off] : 0;
      __syncthreads();
      buf[t] += other;
      __syncthreads();
    }
    if (idx < NA) offs[idx + 1] = carry_s + buf[t];
    __syncthreads();
    if (t == 1023) carry_s += buf[1023];
    __syncthreads();
  }
}

__global__ __launch_bounds__(256) void fill_kernel(
    const int* __restrict__ nbrs, const float* __restrict__ fcut,
    const int* __restrict__ offs, int* __restrict__ cursor,
    int* __restrict__ csr_eid, int* __restrict__ csr_j) {
  int e = blockIdx.x * 256 + threadIdx.x;
  if (e >= NE) return;
  if (fcut[e] <= 0.0f) return;
  int i = nbrs[2 * e];
  int pos = offs[i] + atomicAdd(&cursor[i], 1);
  csr_eid[pos] = e;
  csr_j[pos] = nbrs[2 * e + 1];
}

// ---------------- init: s = emb[z], v = 0 ----------------
__global__ __launch_bounds__(256) void init_kernel(
    const float* __restrict__ emb, const int* __restrict__ z,
    float* __restrict__ s, float* __restrict__ vA) {
  int t = blockIdx.x * 256 + threadIdx.x;
  if (t < NA * 3 * FDIM) vA[t] = 0.0f;
  if (t < NA * FDIM) {
    int n = t >> 7, f = t & 127;
    s[t] = emb[z[n] * FDIM + f];
  }
}

// ---------------- weight pack: W[K][N] fp32 -> B-fragment bf16 layout ----------------
// dst[lay][ ((kb*(N/16) + nt)*64 + l)*8 + j ] = bf16(W[lay][kb*32 + (l>>4)*8 + j][nt*16 + (l&15)])
__global__ __launch_bounds__(256) void pack_kernel(
    const float* __restrict__ src, unsigned short* __restrict__ dst,
    int K, int N, int layers) {
  int t = blockIdx.x * 256 + threadIdx.x;
  int per = K * N;
  if (t >= per * layers) return;
  int lay = t / per;
  int kn = t - lay * per;
  int k = kn / N, n = kn - k * N;
  unsigned short b = f2bf(src[t]);
  int kb = k >> 5, q = (k >> 3) & 3, j = k & 7, nt = n >> 4, c = n & 15;
  int NT = N >> 4;
  dst[(size_t)lay * per + (((kb * NT + nt) * 64 + (q * 16 + c)) * 8 + j)] = b;
}

// ---------------- message MLP via MFMA: phi = silu(s@W1+b1)@W2+b2 ----------------
__global__ __launch_bounds__(256) void msg_mfma_kernel(
    const float* __restrict__ s, const unsigned short* __restrict__ pW1,
    const float* __restrict__ b1, const unsigned short* __restrict__ pW2,
    const float* __restrict__ b2, float* __restrict__ phi) {
  __shared__ bf16x8 sA[4 * 64];  // A-frags [kb][lane]
  __shared__ bf16x8 hA[4 * 64];
  int a0 = blockIdx.x * 16;
  int t = threadIdx.x;
  int lane = t & 63, w = t >> 6;
  {  // stage s tile as packed A-fragments
    int kb = t >> 6, l = t & 63;
    int m = l & 15, q = l >> 4;
    const float* sp = s + (size_t)(a0 + m) * FDIM + kb * 32 + q * 8;
    bf16x8 c;
#pragma unroll
    for (int j = 0; j < 8; j++) c[j] = (short)f2bf(sp[j]);
    sA[kb * 64 + l] = c;
  }
  __syncthreads();
  f32x4 accH[2];
#pragma unroll
  for (int t2 = 0; t2 < 2; t2++)
#pragma unroll
    for (int r = 0; r < 4; r++) accH[t2][r] = 0.0f;
  const bf16x8* W1f = (const bf16x8*)pW1;
#pragma unroll
  for (int kb = 0; kb < 4; kb++) {
    bf16x8 a = sA[kb * 64 + lane];
#pragma unroll
    for (int t2 = 0; t2 < 2; t2++) {
      bf16x8 b = W1f[(kb * 8 + 2 * w + t2) * 64 + lane];
      accH[t2] = __builtin_amdgcn_mfma_f32_16x16x32_bf16(a, b, accH[t2], 0, 0, 0);
    }
  }
  short* hs = (short*)hA;
#pragma unroll
  for (int t2 = 0; t2 < 2; t2++) {
    int n = w * 32 + t2 * 16 + (lane & 15);
    int kb = n >> 5, q = (n >> 3) & 3, j = n & 7;
    float bias = b1[n];
#pragma unroll
    for (int r = 0; r < 4; r++) {
      int m = (lane >> 4) * 4 + r;
      hs[(kb * 64 + q * 16 + m) * 8 + j] = (short)f2bf(silu_f(accH[t2][r] + bias));
    }
  }
  __syncthreads();
  f32x4 accP[6];
#pragma unroll
  for (int t6 = 0; t6 < 6; t6++)
#pragma unroll
    for (int r = 0; r < 4; r++) accP[t6][r] = 0.0f;
  const bf16x8* W2f = (const bf16x8*)pW2;
#pragma unroll
  for (int kb = 0; kb < 4; kb++) {
    bf16x8 a = hA[kb * 64 + lane];
#pragma unroll
    for (int t6 = 0; t6 < 6; t6++) {
      bf16x8 b = W2f[(kb * 24 + 6 * w + t6) * 64 + lane];
      accP[t6] = __builtin_amdgcn_mfma_f32_16x16x32_bf16(a, b, accP[t6], 0, 0, 0);
    }
  }
#pragma unroll
  for (int t6 = 0; t6 < 6; t6++) {
    int n = (6 * w + t6) * 16 + (lane & 15);
    float bias = b2[n];
#pragma unroll
    for (int r = 0; r < 4; r++) {
      int m = (lane >> 4) * 4 + r;
      phi[(size_t)(a0 + m) * F3 + n] = accP[t6][r] + bias;
    }
  }
}

// ---------------- edge aggregation (unchanged, fp32) ----------------
__global__ __launch_bounds__(128) void edge_kernel(
    const float* __restrict__ phi, const float* __restrict__ v_in,
    float* __restrict__ v_out, float* __restrict__ s,
    const float* __restrict__ dW, const float* __restrict__ db,
    const int* __restrict__ offs, const int* __restrict__ csr_eid,
    const int* __restrict__ csr_j, const float* __restrict__ rbfc,
    const float* __restrict__ fcut, const float* __restrict__ unitv) {
  int i = blockIdx.x;
  int f = threadIdx.x;
  float wd0[NRBF], wd1[NRBF], wd2[NRBF];
#pragma unroll
  for (int k = 0; k < NRBF; k++) {
    wd0[k] = dW[k * F3 + f];
    wd1[k] = dW[k * F3 + FDIM + f];
    wd2[k] = dW[k * F3 + 2 * FDIM + f];
  }
  float db0 = db[f], db1 = db[FDIM + f], db2 = db[2 * FDIM + f];
  float acc_s = 0.f, av0 = 0.f, av1 = 0.f, av2 = 0.f;
  int p0 = offs[i], p1 = offs[i + 1];
  for (int p = p0; p < p1; p++) {
    int eid = csr_eid[p];
    int j = csr_j[p];
    float fc = fcut[eid];
    float ux = unitv[3 * eid + 0], uy = unitv[3 * eid + 1], uz = unitv[3 * eid + 2];
    const float* rb = rbfc + eid * NRBF;
    float w0 = db0 * fc, w1 = db1 * fc, w2 = db2 * fc;
#pragma unroll
    for (int k = 0; k < NRBF; k++) {
      float r = rb[k];
      w0 += r * wd0[k]; w1 += r * wd1[k]; w2 += r * wd2[k];
    }
    const float* ph = phi + (size_t)j * F3;
    float i0 = ph[f] * w0;
    float i1 = ph[FDIM + f] * w1;
    float i2 = ph[2 * FDIM + f] * w2;
    const float* vj = v_in + (size_t)j * 3 * FDIM;
    acc_s += i0;
    av0 += i1 * vj[f] + i2 * ux;
    av1 += i1 * vj[FDIM + f] + i2 * uy;
    av2 += i1 * vj[2 * FDIM + f] + i2 * uz;
  }
  s[(size_t)i * FDIM + f] += acc_s;
  const float* vi = v_in + (size_t)i * 3 * FDIM;
  float* vo = v_out + (size_t)i * 3 * FDIM;
  vo[f] = vi[f] + av0;
  vo[FDIM + f] = vi[FDIM + f] + av1;
  vo[2 * FDIM + f] = vi[2 * FDIM + f] + av2;
}

// ---------------- update block via MFMA ----------------
__global__ __launch_bounds__(256) void upd_mfma_kernel(
    float* __restrict__ s, float* __restrict__ v,
    const unsigned short* __restrict__ pU, const unsigned short* __restrict__ pV,
    const unsigned short* __restrict__ pW1, const float* __restrict__ b1,
    const unsigned short* __restrict__ pW2, const float* __restrict__ b2) {
  __shared__ bf16x8 vAf[3 * 4 * 64];  // [rt(c)][kb][lane]
  __shared__ bf16x8 catA[8 * 64];     // k<128 = s, k>=128 = vnorm
  __shared__ bf16x8 hA[4 * 64];
  int a0 = blockIdx.x * 16;
  int t = threadIdx.x;
  int lane = t & 63, w = t >> 6;
  {  // stage v (3 frags) and s (1 frag) per thread
    int l = t & 63, kb = (t >> 6) & 3;
    int m = l & 15, q = l >> 4;
#pragma unroll
    for (int rt = 0; rt < 3; rt++) {
      const float* vp = v + (size_t)(a0 + m) * F3 + rt * FDIM + kb * 32 + q * 8;
      bf16x8 c;
#pragma unroll
      for (int j = 0; j < 8; j++) c[j] = (short)f2bf(vp[j]);
      vAf[(rt * 4 + kb) * 64 + l] = c;
    }
    const float* sp = s + (size_t)(a0 + m) * FDIM + kb * 32 + q * 8;
    bf16x8 c;
#pragma unroll
    for (int j = 0; j < 8; j++) c[j] = (short)f2bf(sp[j]);
    catA[kb * 64 + l] = c;
  }
  __syncthreads();
  // ---- U/V einsum: out cols [32w, 32w+32) ----
  f32x4 accU[3][2], accV[3][2];
#pragma unroll
  for (int rt = 0; rt < 3; rt++)
#pragma unroll
    for (int t2 = 0; t2 < 2; t2++)
#pragma unroll
      for (int r = 0; r < 4; r++) { accU[rt][t2][r] = 0.0f; accV[rt][t2][r] = 0.0f; }
  const bf16x8* Uf = (const bf16x8*)pU;
  const bf16x8* Vf = (const bf16x8*)pV;
#pragma unroll
  for (int kb = 0; kb < 4; kb++) {
    bf16x8 bu[2], bv[2];
#pragma unroll
    for (int t2 = 0; t2 < 2; t2++) {
      bu[t2] = Uf[(kb * 8 + 2 * w + t2) * 64 + lane];
      bv[t2] = Vf[(kb * 8 + 2 * w + t2) * 64 + lane];
    }
#pragma unroll
    for (int rt = 0; rt < 3; rt++) {
      bf16x8 a = vAf[(rt * 4 + kb) * 64 + lane];
#pragma unroll
      for (int t2 = 0; t2 < 2; t2++) {
        accU[rt][t2] = __builtin_amdgcn_mfma_f32_16x16x32_bf16(a, bu[t2], accU[rt][t2], 0, 0, 0);
        accV[rt][t2] = __builtin_amdgcn_mfma_f32_16x16x32_bf16(a, bv[t2], accV[rt][t2], 0, 0, 0);
      }
    }
  }
  // ---- vnorm -> catA (k = 128+g) ----
  short* cs = (short*)catA;
#pragma unroll
  for (int t2 = 0; t2 < 2; t2++) {
    int g = w * 32 + t2 * 16 + (lane & 15);
    int k = 128 + g;
    int kb = k >> 5, q = (k >> 3) & 3, j = k & 7;
#pragma unroll
    for (int r = 0; r < 4; r++) {
      int m = (lane >> 4) * 4 + r;
      float x0 = accV[0][t2][r], x1 = accV[1][t2][r], x2 = accV[2][t2][r];
      cs[(kb * 64 + q * 16 + m) * 8 + j] = (short)f2bf(sqrtf(x0 * x0 + x1 * x1 + x2 * x2 + EPS_F));
    }
  }
  __syncthreads();
  // ---- W1: [16x256]@[256x128] ----
  f32x4 accH[2];
#pragma unroll
  for (int t2 = 0; t2 < 2; t2++)
#pragma unroll
    for (int r = 0; r < 4; r++) accH[t2][r] = 0.0f;
  const bf16x8* W1f = (const bf16x8*)pW1;
#pragma unroll
  for (int kb = 0; kb < 8; kb++) {
    bf16x8 a = catA[kb * 64 + lane];
#pragma unroll
    for (int t2 = 0; t2 < 2; t2++) {
      bf16x8 b = W1f[(kb * 8 + 2 * w + t2) * 64 + lane];
      accH[t2] = __builtin_amdgcn_mfma_f32_16x16x32_bf16(a, b, accH[t2], 0, 0, 0);
    }
  }
  short* hs = (short*)hA;
#pragma unroll
  for (int t2 = 0; t2 < 2; t2++) {
    int n = w * 32 + t2 * 16 + (lane & 15);
    int kb = n >> 5, q = (n >> 3) & 3, j = n & 7;
    float bias = b1[n];
#pragma unroll
    for (int r = 0; r < 4; r++) {
      int m = (lane >> 4) * 4 + r;
      hs[(kb * 64 + q * 16 + m) * 8 + j] = (short)f2bf(silu_f(accH[t2][r] + bias));
    }
  }
  __syncthreads();
  // ---- W2: [16x128]@[128x384]; wave covers cols {g, 128+g, 256+g} for g in [32w,32w+32) ----
  f32x4 accA[3][2];
#pragma unroll
  for (int c3 = 0; c3 < 3; c3++)
#pragma unroll
    for (int t2 = 0; t2 < 2; t2++)
#pragma unroll
      for (int r = 0; r < 4; r++) accA[c3][t2][r] = 0.0f;
  const bf16x8* W2f = (const bf16x8*)pW2;
#pragma unroll
  for (int kb = 0; kb < 4; kb++) {
    bf16x8 a = hA[kb * 64 + lane];
#pragma unroll
    for (int c3 = 0; c3 < 3; c3++)
#pragma unroll
      for (int t2 = 0; t2 < 2; t2++) {
        bf16x8 b = W2f[(kb * 24 + c3 * 8 + 2 * w + t2) * 64 + lane];
        accA[c3][t2] = __builtin_amdgcn_mfma_f32_16x16x32_bf16(a, b, accA[c3][t2], 0, 0, 0);
      }
  }
  // ---- epilogue ----
#pragma unroll
  for (int t2 = 0; t2 < 2; t2++) {
    int g = w * 32 + t2 * 16 + (lane & 15);
    float bb0 = b2[g], bb1 = b2[FDIM + g], bb2 = b2[2 * FDIM + g];
#pragma unroll
    for (int r = 0; r < 4; r++) {
      int m = (lane >> 4) * 4 + r;
      int n = a0 + m;
      float a0v = accA[0][t2][r] + bb0;
      float a1v = accA[1][t2][r] + bb1;
      float a2v = accA[2][t2][r] + bb2;
      float dot = accU[0][t2][r] * accV[0][t2][r] + accU[1][t2][r] * accV[1][t2][r] +
                  accU[2][t2][r] * accV[2][t2][r];
      s[(size_t)n * FDIM + g] += a1v * dot + a2v;
#pragma unroll
      for (int c = 0; c < 3; c++) {
        size_t ix = (size_t)n * F3 + c * FDIM + g;
        v[ix] += a0v * accU[c][t2][r];
      }
    }
  }
}

// ---------------- readout (unchanged) ----------------
__global__ __launch_bounds__(64) void readout_kernel(
    const float* __restrict__ s, const float* __restrict__ W1, const float* __restrict__ b1,
    const float* __restrict__ W2, const float* __restrict__ b2,
    const int* __restrict__ mol_idx, float* __restrict__ out) {
  int n = blockIdx.x;
  int t = threadIdx.x;
  float acc = b1[t];
  const float* sr = s + (size_t)n * FDIM;
  for (int k = 0; k < FDIM; k++) acc += sr[k] * W1[k * FH + t];
  float val = silu_f(acc) * W2[t];
#pragma unroll
  for (int off = 32; off > 0; off >>= 1) val += __shfl_down(val, off, 64);
  if (t == 0) atomicAdd(&out[mol_idx[n]], val + b2[0]);
}

extern "C" void kernel_launch(void* const* d_in, const int* in_sizes, int n_in,
                              void* d_out, int out_size, void* d_ws, size_t ws_size,
                              hipStream_t stream) {
  const float* xyz = (const float*)d_in[0];
  const int* z = (const int*)d_in[1];
  const int* nbrs = (const int*)d_in[2];
  const int* mol = (const int*)d_in[3];
  const float* emb = (const float*)d_in[4];
  const float* msgW1 = (const float*)d_in[5];
  const float* msgb1 = (const float*)d_in[6];
  const float* msgW2 = (const float*)d_in[7];
  const float* msgb2 = (const float*)d_in[8];
  const float* distW = (const float*)d_in[9];
  const float* distb = (const float*)d_in[10];
  const float* updU = (const float*)d_in[11];
  const float* updV = (const float*)d_in[12];
  const float* updW1 = (const float*)d_in[13];
  const float* updb1 = (const float*)d_in[14];
  const float* updW2 = (const float*)d_in[15];
  const float* updb2 = (const float*)d_in[16];
  const float* rW1 = (const float*)d_in[17];
  const float* rb1 = (const float*)d_in[18];
  const float* rW2 = (const float*)d_in[19];
  const float* rb2 = (const float*)d_in[20];

  float* ws = (float*)d_ws;
  float* s = ws;      ws += (size_t)NA * FDIM;
  float* vA = ws;     ws += (size_t)NA * 3 * FDIM;
  float* vB = ws;     ws += (size_t)NA * 3 * FDIM;
  float* phi = ws;    ws += (size_t)NA * F3;
  float* rbfc = ws;   ws += (size_t)NE * NRBF;
  float* fcut = ws;   ws += (size_t)NE;
  float* unitv = ws;  ws += (size_t)NE * 3;
  int* counts = (int*)ws;
  int* cursor = counts + NA;
  int* offs = cursor + NA;
  int* csr_eid = offs + NA + 1;
  int* csr_j = csr_eid + NE;
  // packed bf16 weights (16B aligned)
  unsigned short* pk = (unsigned short*)(((uintptr_t)(csr_j + NE) + 15) & ~(uintptr_t)15);
  unsigned short* pMsgW1 = pk;                       // 3*128*128
  unsigned short* pMsgW2 = pMsgW1 + 3 * 128 * 128;   // 3*128*384
  unsigned short* pUpdU  = pMsgW2 + 3 * 128 * 384;
  unsigned short* pUpdV  = pUpdU + 3 * 128 * 128;
  unsigned short* pUpdW1 = pUpdV + 3 * 128 * 128;    // 3*256*128
  unsigned short* pUpdW2 = pUpdW1 + 3 * 256 * 128;   // 3*128*384

  hipMemsetAsync(counts, 0, 2 * NA * sizeof(int), stream);
  hipMemsetAsync(d_out, 0, NMOLS * sizeof(float), stream);

  pack_kernel<<<(3 * 128 * 128 + 255) / 256, 256, 0, stream>>>(msgW1, pMsgW1, 128, 128, 3);
  pack_kernel<<<(3 * 128 * 384 + 255) / 256, 256, 0, stream>>>(msgW2, pMsgW2, 128, 384, 3);
  pack_kernel<<<(3 * 128 * 128 + 255) / 256, 256, 0, stream>>>(updU, pUpdU, 128, 128, 3);
  pack_kernel<<<(3 * 128 * 128 + 255) / 256, 256, 0, stream>>>(updV, pUpdV, 128, 128, 3);
  pack_kernel<<<(3 * 256 * 128 + 255) / 256, 256, 0, stream>>>(updW1, pUpdW1, 256, 128, 3);
  pack_kernel<<<(3 * 128 * 384 + 255) / 256, 256, 0, stream>>>(updW2, pUpdW2, 128, 384, 3);

  geom_kernel<<<NE / 256, 256, 0, stream>>>(xyz, nbrs, unitv, rbfc, fcut);
  count_kernel<<<NE / 256, 256, 0, stream>>>(nbrs, fcut, counts);
  scan_kernel<<<1, 1024, 0, stream>>>(counts, offs);
  fill_kernel<<<NE / 256, 256, 0, stream>>>(nbrs, fcut, offs, cursor, csr_eid, csr_j);
  init_kernel<<<(NA * 3 * FDIM + 255) / 256, 256, 0, stream>>>(emb, z, s, vA);

  float* vin = vA;
  float* vout = vB;
  for (int l = 0; l < NLAYERS; l++) {
    msg_mfma_kernel<<<NA / 16, 256, 0, stream>>>(
        s, pMsgW1 + (size_t)l * 128 * 128, msgb1 + (size_t)l * FDIM,
        pMsgW2 + (size_t)l * 128 * 384, msgb2 + (size_t)l * F3, phi);
    edge_kernel<<<NA, 128, 0, stream>>>(phi, vin, vout, s,
                                        distW + (size_t)l * NRBF * F3,
                                        distb + (size_t)l * F3,
                                        offs, csr_eid, csr_j, rbfc, fcut, unitv);
    upd_mfma_kernel<<<NA / 16, 256, 0, stream>>>(
        s, vout, pUpdU + (size_t)l * 128 * 128, pUpdV + (size_t)l * 128 * 128,
        pUpdW1 + (size_t)l * 256 * 128, updb1 + (size_t)l * FDIM,
        pUpdW2 + (size_t)l * 128 * 384, updb2 + (size_t)l * F3);
    float* tmp = vin; vin = vout; vout = tmp;
  }
  readout_kernel<<<NA, 64, 0, stream>>>(s, rW1, rb1, rW2, rb2, mol, (float*)d_out);
}

// Round 3
// 458.034 us; speedup vs baseline: 1.4987x; 1.0198x over previous
//
#include <hip/hip_runtime.h>
#include <hip/hip_bf16.h>
#include <math.h>

#define NA 10000
#define NE 256000
#define FDIM 128
#define F3 384
#define NRBF 20
#define NLAYERS 3
#define NMOLS 100
#define FH 64
#define CUTOFF_F 5.0f
#define EPS_F 1e-8f
#define PI_F 3.14159265358979323846f

typedef __attribute__((ext_vector_type(8))) short bf16x8;
typedef __attribute__((ext_vector_type(4))) float f32x4;

__device__ __forceinline__ float silu_f(float x) { return x / (1.0f + expf(-x)); }

__device__ __forceinline__ unsigned short f2bf(float x) {
  unsigned u = __float_as_uint(x);
  return (unsigned short)((u + 0x7FFFu + ((u >> 16) & 1u)) >> 16);
}

// ---------------- geometry (layer-invariant, per edge) ----------------
__global__ __launch_bounds__(256) void geom_kernel(
    const float* __restrict__ xyz, const int* __restrict__ nbrs,
    float* __restrict__ unitv, float* __restrict__ rbfc, float* __restrict__ fcut) {
  int e = blockIdx.x * 256 + threadIdx.x;
  if (e >= NE) return;
  int i = nbrs[2 * e + 0], j = nbrs[2 * e + 1];
  float rx = xyz[3 * j + 0] - xyz[3 * i + 0];
  float ry = xyz[3 * j + 1] - xyz[3 * i + 1];
  float rz = xyz[3 * j + 2] - xyz[3 * i + 2];
  float d = sqrtf(rx * rx + ry * ry + rz * rz + EPS_F);
  float invd = 1.0f / d;
  unitv[3 * e + 0] = rx * invd;
  unitv[3 * e + 1] = ry * invd;
  unitv[3 * e + 2] = rz * invd;
  float fc = 0.0f;
  if (d < CUTOFF_F) fc = 0.5f * (cosf(PI_F * d / CUTOFF_F) + 1.0f);
  fcut[e] = fc;
  float base = PI_F * d / CUTOFF_F;
  float sc = invd * fc;
#pragma unroll
  for (int k = 0; k < NRBF; k++) rbfc[e * NRBF + k] = sinf((float)(k + 1) * base) * sc;
}

// ---------------- CSR build over idx_i (skip fcut==0 edges) ----------------
__global__ __launch_bounds__(256) void count_kernel(
    const int* __restrict__ nbrs, const float* __restrict__ fcut, int* __restrict__ counts) {
  int e = blockIdx.x * 256 + threadIdx.x;
  if (e >= NE) return;
  if (fcut[e] > 0.0f) atomicAdd(&counts[nbrs[2 * e]], 1);
}

__global__ __launch_bounds__(1024) void scan_kernel(const int* __restrict__ counts,
                                                    int* __restrict__ offs) {
  __shared__ int buf[1024];
  __shared__ int carry_s;
  int t = threadIdx.x;
  if (t == 0) { carry_s = 0; offs[0] = 0; }
  __syncthreads();
  for (int base = 0; base < NA; base += 1024) {
    int idx = base + t;
    int val = (idx < NA) ? counts[idx] : 0;
    buf[t] = val;
    __syncthreads();
    for (int off = 1; off < 1024; off <<= 1) {
      int other = (t >= off) ? buf[t - off] : 0;
      __syncthreads();
      buf[t] += other;
      __syncthreads();
    }
    if (idx < NA) offs[idx + 1] = carry_s + buf[t];
    __syncthreads();
    if (t == 1023) carry_s += buf[1023];
    __syncthreads();
  }
}

__global__ __launch_bounds__(256) void fill_kernel(
    const int* __restrict__ nbrs, const float* __restrict__ fcut,
    const int* __restrict__ offs, int* __restrict__ cursor,
    int* __restrict__ csr_eid, int* __restrict__ csr_j) {
  int e = blockIdx.x * 256 + threadIdx.x;
  if (e >= NE) return;
  if (fcut[e] <= 0.0f) return;
  int i = nbrs[2 * e];
  int pos = offs[i] + atomicAdd(&cursor[i], 1);
  csr_eid[pos] = e;
  csr_j[pos] = nbrs[2 * e + 1];
}

// ---------------- init: s = emb[z], v = 0 ----------------
__global__ __launch_bounds__(256) void init_kernel(
    const float* __restrict__ emb, const int* __restrict__ z,
    float* __restrict__ s, float* __restrict__ vA) {
  int t = blockIdx.x * 256 + threadIdx.x;
  if (t < NA * 3 * FDIM) vA[t] = 0.0f;
  if (t < NA * FDIM) {
    int n = t >> 7, f = t & 127;
    s[t] = emb[z[n] * FDIM + f];
  }
}

// ---------------- weight pack: W[K][N] fp32 -> B-fragment bf16 layout ----------------
__global__ __launch_bounds__(256) void pack_kernel(
    const float* __restrict__ src, unsigned short* __restrict__ dst,
    int K, int N, int layers) {
  int t = blockIdx.x * 256 + threadIdx.x;
  int per = K * N;
  if (t >= per * layers) return;
  int lay = t / per;
  int kn = t - lay * per;
  int k = kn / N, n = kn - k * N;
  unsigned short b = f2bf(src[t]);
  int kb = k >> 5, q = (k >> 3) & 3, j = k & 7, nt = n >> 4, c = n & 15;
  int NT = N >> 4;
  dst[(size_t)lay * per + (((kb * NT + nt) * 64 + (q * 16 + c)) * 8 + j)] = b;
}

// ---------------- message MLP via MFMA: phi = silu(s@W1+b1)@W2+b2 ----------------
__global__ __launch_bounds__(256) void msg_mfma_kernel(
    const float* __restrict__ s, const unsigned short* __restrict__ pW1,
    const float* __restrict__ b1, const unsigned short* __restrict__ pW2,
    const float* __restrict__ b2, float* __restrict__ phi) {
  __shared__ bf16x8 sA[4 * 64];
  __shared__ bf16x8 hA[4 * 64];
  int a0 = blockIdx.x * 16;
  int t = threadIdx.x;
  int lane = t & 63, w = t >> 6;
  {
    int kb = t >> 6, l = t & 63;
    int m = l & 15, q = l >> 4;
    const float* sp = s + (size_t)(a0 + m) * FDIM + kb * 32 + q * 8;
    bf16x8 c;
#pragma unroll
    for (int j = 0; j < 8; j++) c[j] = (short)f2bf(sp[j]);
    sA[kb * 64 + l] = c;
  }
  __syncthreads();
  f32x4 accH[2];
#pragma unroll
  for (int t2 = 0; t2 < 2; t2++)
#pragma unroll
    for (int r = 0; r < 4; r++) accH[t2][r] = 0.0f;
  const bf16x8* W1f = (const bf16x8*)pW1;
#pragma unroll
  for (int kb = 0; kb < 4; kb++) {
    bf16x8 a = sA[kb * 64 + lane];
#pragma unroll
    for (int t2 = 0; t2 < 2; t2++) {
      bf16x8 b = W1f[(kb * 8 + 2 * w + t2) * 64 + lane];
      accH[t2] = __builtin_amdgcn_mfma_f32_16x16x32_bf16(a, b, accH[t2], 0, 0, 0);
    }
  }
  short* hs = (short*)hA;
#pragma unroll
  for (int t2 = 0; t2 < 2; t2++) {
    int n = w * 32 + t2 * 16 + (lane & 15);
    int kb = n >> 5, q = (n >> 3) & 3, j = n & 7;
    float bias = b1[n];
#pragma unroll
    for (int r = 0; r < 4; r++) {
      int m = (lane >> 4) * 4 + r;
      hs[(kb * 64 + q * 16 + m) * 8 + j] = (short)f2bf(silu_f(accH[t2][r] + bias));
    }
  }
  __syncthreads();
  f32x4 accP[6];
#pragma unroll
  for (int t6 = 0; t6 < 6; t6++)
#pragma unroll
    for (int r = 0; r < 4; r++) accP[t6][r] = 0.0f;
  const bf16x8* W2f = (const bf16x8*)pW2;
#pragma unroll
  for (int kb = 0; kb < 4; kb++) {
    bf16x8 a = hA[kb * 64 + lane];
#pragma unroll
    for (int t6 = 0; t6 < 6; t6++) {
      bf16x8 b = W2f[(kb * 24 + 6 * w + t6) * 64 + lane];
      accP[t6] = __builtin_amdgcn_mfma_f32_16x16x32_bf16(a, b, accP[t6], 0, 0, 0);
    }
  }
#pragma unroll
  for (int t6 = 0; t6 < 6; t6++) {
    int n = (6 * w + t6) * 16 + (lane & 15);
    float bias = b2[n];
#pragma unroll
    for (int r = 0; r < 4; r++) {
      int m = (lane >> 4) * 4 + r;
      phi[(size_t)(a0 + m) * F3 + n] = accP[t6][r] + bias;
    }
  }
}

// ---------------- edge aggregation (fp32, CSR, no atomics) ----------------
__global__ __launch_bounds__(128) void edge_kernel(
    const float* __restrict__ phi, const float* __restrict__ v_in,
    float* __restrict__ v_out, float* __restrict__ s,
    const float* __restrict__ dW, const float* __restrict__ db,
    const int* __restrict__ offs, const int* __restrict__ csr_eid,
    const int* __restrict__ csr_j, const float* __restrict__ rbfc,
    const float* __restrict__ fcut, const float* __restrict__ unitv) {
  int i = blockIdx.x;
  int f = threadIdx.x;
  float wd0[NRBF], wd1[NRBF], wd2[NRBF];
#pragma unroll
  for (int k = 0; k < NRBF; k++) {
    wd0[k] = dW[k * F3 + f];
    wd1[k] = dW[k * F3 + FDIM + f];
    wd2[k] = dW[k * F3 + 2 * FDIM + f];
  }
  float db0 = db[f], db1 = db[FDIM + f], db2 = db[2 * FDIM + f];
  float acc_s = 0.f, av0 = 0.f, av1 = 0.f, av2 = 0.f;
  int p0 = offs[i], p1 = offs[i + 1];
  for (int p = p0; p < p1; p++) {
    int eid = csr_eid[p];
    int j = csr_j[p];
    float fc = fcut[eid];
    float ux = unitv[3 * eid + 0], uy = unitv[3 * eid + 1], uz = unitv[3 * eid + 2];
    const float* rb = rbfc + eid * NRBF;
    float w0 = db0 * fc, w1 = db1 * fc, w2 = db2 * fc;
#pragma unroll
    for (int k = 0; k < NRBF; k++) {
      float r = rb[k];
      w0 += r * wd0[k]; w1 += r * wd1[k]; w2 += r * wd2[k];
    }
    const float* ph = phi + (size_t)j * F3;
    float i0 = ph[f] * w0;
    float i1 = ph[FDIM + f] * w1;
    float i2 = ph[2 * FDIM + f] * w2;
    const float* vj = v_in + (size_t)j * 3 * FDIM;
    acc_s += i0;
    av0 += i1 * vj[f] + i2 * ux;
    av1 += i1 * vj[FDIM + f] + i2 * uy;
    av2 += i1 * vj[2 * FDIM + f] + i2 * uz;
  }
  s[(size_t)i * FDIM + f] += acc_s;
  const float* vi = v_in + (size_t)i * 3 * FDIM;
  float* vo = v_out + (size_t)i * 3 * FDIM;
  vo[f] = vi[f] + av0;
  vo[FDIM + f] = vi[FDIM + f] + av1;
  vo[2 * FDIM + f] = vi[2 * FDIM + f] + av2;
}

// ---------------- update block via MFMA ----------------
__global__ __launch_bounds__(256) void upd_mfma_kernel(
    float* __restrict__ s, float* __restrict__ v,
    const unsigned short* __restrict__ pU, const unsigned short* __restrict__ pV,
    const unsigned short* __restrict__ pW1, const float* __restrict__ b1,
    const unsigned short* __restrict__ pW2, const float* __restrict__ b2) {
  __shared__ bf16x8 vAf[3 * 4 * 64];
  __shared__ bf16x8 catA[8 * 64];
  __shared__ bf16x8 hA[4 * 64];
  int a0 = blockIdx.x * 16;
  int t = threadIdx.x;
  int lane = t & 63, w = t >> 6;
  {
    int l = t & 63, kb = (t >> 6) & 3;
    int m = l & 15, q = l >> 4;
#pragma unroll
    for (int rt = 0; rt < 3; rt++) {
      const float* vp = v + (size_t)(a0 + m) * F3 + rt * FDIM + kb * 32 + q * 8;
      bf16x8 c;
#pragma unroll
      for (int j = 0; j < 8; j++) c[j] = (short)f2bf(vp[j]);
      vAf[(rt * 4 + kb) * 64 + l] = c;
    }
    const float* sp = s + (size_t)(a0 + m) * FDIM + kb * 32 + q * 8;
    bf16x8 c;
#pragma unroll
    for (int j = 0; j < 8; j++) c[j] = (short)f2bf(sp[j]);
    catA[kb * 64 + l] = c;
  }
  __syncthreads();
  f32x4 accU[3][2], accV[3][2];
#pragma unroll
  for (int rt = 0; rt < 3; rt++)
#pragma unroll
    for (int t2 = 0; t2 < 2; t2++)
#pragma unroll
      for (int r = 0; r < 4; r++) { accU[rt][t2][r] = 0.0f; accV[rt][t2][r] = 0.0f; }
  const bf16x8* Uf = (const bf16x8*)pU;
  const bf16x8* Vf = (const bf16x8*)pV;
#pragma unroll
  for (int kb = 0; kb < 4; kb++) {
    bf16x8 bu[2], bv[2];
#pragma unroll
    for (int t2 = 0; t2 < 2; t2++) {
      bu[t2] = Uf[(kb * 8 + 2 * w + t2) * 64 + lane];
      bv[t2] = Vf[(kb * 8 + 2 * w + t2) * 64 + lane];
    }
#pragma unroll
    for (int rt = 0; rt < 3; rt++) {
      bf16x8 a = vAf[(rt * 4 + kb) * 64 + lane];
#pragma unroll
      for (int t2 = 0; t2 < 2; t2++) {
        accU[rt][t2] = __builtin_amdgcn_mfma_f32_16x16x32_bf16(a, bu[t2], accU[rt][t2], 0, 0, 0);
        accV[rt][t2] = __builtin_amdgcn_mfma_f32_16x16x32_bf16(a, bv[t2], accV[rt][t2], 0, 0, 0);
      }
    }
  }
  short* cs = (short*)catA;
#pragma unroll
  for (int t2 = 0; t2 < 2; t2++) {
    int g = w * 32 + t2 * 16 + (lane & 15);
    int k = 128 + g;
    int kb = k >> 5, q = (k >> 3) & 3, j = k & 7;
#pragma unroll
    for (int r = 0; r < 4; r++) {
      int m = (lane >> 4) * 4 + r;
      float x0 = accV[0][t2][r], x1 = accV[1][t2][r], x2 = accV[2][t2][r];
      cs[(kb * 64 + q * 16 + m) * 8 + j] = (short)f2bf(sqrtf(x0 * x0 + x1 * x1 + x2 * x2 + EPS_F));
    }
  }
  __syncthreads();
  f32x4 accH[2];
#pragma unroll
  for (int t2 = 0; t2 < 2; t2++)
#pragma unroll
    for (int r = 0; r < 4; r++) accH[t2][r] = 0.0f;
  const bf16x8* W1f = (const bf16x8*)pW1;
#pragma unroll
  for (int kb = 0; kb < 8; kb++) {
    bf16x8 a = catA[kb * 64 + lane];
#pragma unroll
    for (int t2 = 0; t2 < 2; t2++) {
      bf16x8 b = W1f[(kb * 8 + 2 * w + t2) * 64 + lane];
      accH[t2] = __builtin_amdgcn_mfma_f32_16x16x32_bf16(a, b, accH[t2], 0, 0, 0);
    }
  }
  short* hs = (short*)hA;
#pragma unroll
  for (int t2 = 0; t2 < 2; t2++) {
    int n = w * 32 + t2 * 16 + (lane & 15);
    int kb = n >> 5, q = (n >> 3) & 3, j = n & 7;
    float bias = b1[n];
#pragma unroll
    for (int r = 0; r < 4; r++) {
      int m = (lane >> 4) * 4 + r;
      hs[(kb * 64 + q * 16 + m) * 8 + j] = (short)f2bf(silu_f(accH[t2][r] + bias));
    }
  }
  __syncthreads();
  f32x4 accA[3][2];
#pragma unroll
  for (int c3 = 0; c3 < 3; c3++)
#pragma unroll
    for (int t2 = 0; t2 < 2; t2++)
#pragma unroll
      for (int r = 0; r < 4; r++) accA[c3][t2][r] = 0.0f;
  const bf16x8* W2f = (const bf16x8*)pW2;
#pragma unroll
  for (int kb = 0; kb < 4; kb++) {
    bf16x8 a = hA[kb * 64 + lane];
#pragma unroll
    for (int c3 = 0; c3 < 3; c3++)
#pragma unroll
      for (int t2 = 0; t2 < 2; t2++) {
        bf16x8 b = W2f[(kb * 24 + c3 * 8 + 2 * w + t2) * 64 + lane];
        accA[c3][t2] = __builtin_amdgcn_mfma_f32_16x16x32_bf16(a, b, accA[c3][t2], 0, 0, 0);
      }
  }
#pragma unroll
  for (int t2 = 0; t2 < 2; t2++) {
    int g = w * 32 + t2 * 16 + (lane & 15);
    float bb0 = b2[g], bb1 = b2[FDIM + g], bb2 = b2[2 * FDIM + g];
#pragma unroll
    for (int r = 0; r < 4; r++) {
      int m = (lane >> 4) * 4 + r;
      int n = a0 + m;
      float a0v = accA[0][t2][r] + bb0;
      float a1v = accA[1][t2][r] + bb1;
      float a2v = accA[2][t2][r] + bb2;
      float dot = accU[0][t2][r] * accV[0][t2][r] + accU[1][t2][r] * accV[1][t2][r] +
                  accU[2][t2][r] * accV[2][t2][r];
      s[(size_t)n * FDIM + g] += a1v * dot + a2v;
#pragma unroll
      for (int c = 0; c < 3; c++) {
        size_t ix = (size_t)n * F3 + c * FDIM + g;
        v[ix] += a0v * accU[c][t2][r];
      }
    }
  }
}

// ---------------- readout via MFMA: atom_e = silu(s@W1+b1)@W2+b2, segment-sum ----------------
__global__ __launch_bounds__(256) void readout_mfma_kernel(
    const float* __restrict__ s, const unsigned short* __restrict__ pW1,
    const float* __restrict__ b1, const float* __restrict__ W2, const float* __restrict__ b2,
    const int* __restrict__ mol_idx, float* __restrict__ out) {
  __shared__ bf16x8 sA[4 * 64];
  __shared__ float red[4][16];
  int a0 = blockIdx.x * 16;
  int t = threadIdx.x;
  int lane = t & 63, w = t >> 6;
  {
    int kb = t >> 6, l = t & 63;
    int m = l & 15, q = l >> 4;
    const float* sp = s + (size_t)(a0 + m) * FDIM + kb * 32 + q * 8;
    bf16x8 c;
#pragma unroll
    for (int j = 0; j < 8; j++) c[j] = (short)f2bf(sp[j]);
    sA[kb * 64 + l] = c;
  }
  __syncthreads();
  f32x4 acc;
#pragma unroll
  for (int r = 0; r < 4; r++) acc[r] = 0.0f;
  const bf16x8* W1f = (const bf16x8*)pW1;
#pragma unroll
  for (int kb = 0; kb < 4; kb++) {
    bf16x8 a = sA[kb * 64 + lane];
    bf16x8 b = W1f[(kb * 4 + w) * 64 + lane];  // N=64 -> NT=4, nt=w
    acc = __builtin_amdgcn_mfma_f32_16x16x32_bf16(a, b, acc, 0, 0, 0);
  }
  int col = w * 16 + (lane & 15);
  float bias = b1[col], w2v = W2[col];
  float val[4];
#pragma unroll
  for (int r = 0; r < 4; r++) val[r] = silu_f(acc[r] + bias) * w2v;
#pragma unroll
  for (int off = 1; off < 16; off <<= 1)
#pragma unroll
    for (int r = 0; r < 4; r++) val[r] += __shfl_xor(val[r], off, 64);
  if ((lane & 15) == 0) {
#pragma unroll
    for (int r = 0; r < 4; r++) red[w][(lane >> 4) * 4 + r] = val[r];
  }
  __syncthreads();
  if (t < 16) {
    float sum = red[0][t] + red[1][t] + red[2][t] + red[3][t] + b2[0];
    atomicAdd(&out[mol_idx[a0 + t]], sum);
  }
}

extern "C" void kernel_launch(void* const* d_in, const int* in_sizes, int n_in,
                              void* d_out, int out_size, void* d_ws, size_t ws_size,
                              hipStream_t stream) {
  const float* xyz = (const float*)d_in[0];
  const int* z = (const int*)d_in[1];
  const int* nbrs = (const int*)d_in[2];
  const int* mol = (const int*)d_in[3];
  const float* emb = (const float*)d_in[4];
  const float* msgW1 = (const float*)d_in[5];
  const float* msgb1 = (const float*)d_in[6];
  const float* msgW2 = (const float*)d_in[7];
  const float* msgb2 = (const float*)d_in[8];
  const float* distW = (const float*)d_in[9];
  const float* distb = (const float*)d_in[10];
  const float* updU = (const float*)d_in[11];
  const float* updV = (const float*)d_in[12];
  const float* updW1 = (const float*)d_in[13];
  const float* updb1 = (const float*)d_in[14];
  const float* updW2 = (const float*)d_in[15];
  const float* updb2 = (const float*)d_in[16];
  const float* rW1 = (const float*)d_in[17];
  const float* rb1 = (const float*)d_in[18];
  const float* rW2 = (const float*)d_in[19];
  const float* rb2 = (const float*)d_in[20];

  float* ws = (float*)d_ws;
  float* s = ws;      ws += (size_t)NA * FDIM;
  float* vA = ws;     ws += (size_t)NA * 3 * FDIM;
  float* vB = ws;     ws += (size_t)NA * 3 * FDIM;
  float* phi = ws;    ws += (size_t)NA * F3;
  float* rbfc = ws;   ws += (size_t)NE * NRBF;
  float* fcut = ws;   ws += (size_t)NE;
  float* unitv = ws;  ws += (size_t)NE * 3;
  int* counts = (int*)ws;
  int* cursor = counts + NA;
  int* offs = cursor + NA;
  int* csr_eid = offs + NA + 1;
  int* csr_j = csr_eid + NE;
  unsigned short* pk = (unsigned short*)(((uintptr_t)(csr_j + NE) + 15) & ~(uintptr_t)15);
  unsigned short* pMsgW1 = pk;
  unsigned short* pMsgW2 = pMsgW1 + 3 * 128 * 128;
  unsigned short* pUpdU  = pMsgW2 + 3 * 128 * 384;
  unsigned short* pUpdV  = pUpdU + 3 * 128 * 128;
  unsigned short* pUpdW1 = pUpdV + 3 * 128 * 128;
  unsigned short* pUpdW2 = pUpdW1 + 3 * 256 * 128;
  unsigned short* pRW1   = pUpdW2 + 3 * 128 * 384;   // 128*64

  hipMemsetAsync(counts, 0, 2 * NA * sizeof(int), stream);
  hipMemsetAsync(d_out, 0, NMOLS * sizeof(float), stream);

  pack_kernel<<<(3 * 128 * 128 + 255) / 256, 256, 0, stream>>>(msgW1, pMsgW1, 128, 128, 3);
  pack_kernel<<<(3 * 128 * 384 + 255) / 256, 256, 0, stream>>>(msgW2, pMsgW2, 128, 384, 3);
  pack_kernel<<<(3 * 128 * 128 + 255) / 256, 256, 0, stream>>>(updU, pUpdU, 128, 128, 3);
  pack_kernel<<<(3 * 128 * 128 + 255) / 256, 256, 0, stream>>>(updV, pUpdV, 128, 128, 3);
  pack_kernel<<<(3 * 256 * 128 + 255) / 256, 256, 0, stream>>>(updW1, pUpdW1, 256, 128, 3);
  pack_kernel<<<(3 * 128 * 384 + 255) / 256, 256, 0, stream>>>(updW2, pUpdW2, 128, 384, 3);
  pack_kernel<<<(128 * 64 + 255) / 256, 256, 0, stream>>>(rW1, pRW1, 128, 64, 1);

  geom_kernel<<<NE / 256, 256, 0, stream>>>(xyz, nbrs, unitv, rbfc, fcut);
  count_kernel<<<NE / 256, 256, 0, stream>>>(nbrs, fcut, counts);
  scan_kernel<<<1, 1024, 0, stream>>>(counts, offs);
  fill_kernel<<<NE / 256, 256, 0, stream>>>(nbrs, fcut, offs, cursor, csr_eid, csr_j);
  init_kernel<<<(NA * 3 * FDIM + 255) / 256, 256, 0, stream>>>(emb, z, s, vA);

  float* vin = vA;
  float* vout = vB;
  for (int l = 0; l < NLAYERS; l++) {
    msg_mfma_kernel<<<NA / 16, 256, 0, stream>>>(
        s, pMsgW1 + (size_t)l * 128 * 128, msgb1 + (size_t)l * FDIM,
        pMsgW2 + (size_t)l * 128 * 384, msgb2 + (size_t)l * F3, phi);
    edge_kernel<<<NA, 128, 0, stream>>>(phi, vin, vout, s,
                                        distW + (size_t)l * NRBF * F3,
                                        distb + (size_t)l * F3,
                                        offs, csr_eid, csr_j, rbfc, fcut, unitv);
    upd_mfma_kernel<<<NA / 16, 256, 0, stream>>>(
        s, vout, pUpdU + (size_t)l * 128 * 128, pUpdV + (size_t)l * 128 * 128,
        pUpdW1 + (size_t)l * 256 * 128, updb1 + (size_t)l * FDIM,
        pUpdW2 + (size_t)l * 128 * 384, updb2 + (size_t)l * F3);
    float* tmp = vin; vin = vout; vout = tmp;
  }
  readout_mfma_kernel<<<NA / 16, 256, 0, stream>>>(s, pRW1, rb1, rW2, rb2, mol, (float*)d_out);
}